// Round 11
// baseline (127.976 us; speedup 1.0000x reference)
//
#include <hip/hip_runtime.h>

typedef __bf16 bf16x8 __attribute__((ext_vector_type(8)));
typedef float f32x4 __attribute__((ext_vector_type(4)));

#define BN_EPS 1e-5f

__device__ __forceinline__ unsigned short f2bf(float f) {
    union { float f; unsigned u; } x; x.f = f;
    unsigned r = x.u + 0x7fffu + ((x.u >> 16) & 1u);
    return (unsigned short)(r >> 16);
}

__device__ __forceinline__ unsigned pk_bf16(float lo, float hi) {
    unsigned r;
    asm("v_cvt_pk_bf16_f32 %0, %1, %2" : "=v"(r) : "v"(lo), "v"(hi));
    return r;
}

__device__ __forceinline__ float fcomp(float4 v, int j) {
    return (j == 0) ? v.x : (j == 1) ? v.y : (j == 2) ? v.z : v.w;
}

// ---------------- prepass: fold BN scale into weights, FRAGMENT-CONTIGUOUS layout ----
__global__ void prep_kernel(const float* __restrict__ pw0, const float* __restrict__ pw1,
                            const float* __restrict__ w2,
                            const float* __restrict__ s0, const float* __restrict__ b0,
                            const float* __restrict__ m0, const float* __restrict__ v0,
                            const float* __restrict__ s1, const float* __restrict__ b1,
                            const float* __restrict__ m1, const float* __restrict__ v1,
                            const float* __restrict__ s2, const float* __restrict__ b2,
                            const float* __restrict__ m2, const float* __restrict__ v2,
                            unsigned short* __restrict__ wfF0, unsigned short* __restrict__ wfF1,
                            unsigned short* __restrict__ wfF2, float* __restrict__ beta) {
    int o = blockIdx.x;
    int t = threadIdx.x;
    float inv0 = s0[o] * rsqrtf(v0[o] + BN_EPS);
    float inv1 = s1[o] * rsqrtf(v1[o] + BN_EPS);
    float inv2 = s2[o] * rsqrtf(v2[o] + BN_EPS);
    if (t == 0) {
        beta[0 * 256 + o] = b0[o] - m0[o] * inv0;
        beta[1 * 256 + o] = b1[o] - m1[o] * inv1;
        beta[2 * 256 + o] = b2[o] - m2[o] * inv2;
    }
    if (t < 128) {
        wfF0[((t >> 3) * 256 + o) * 8 + (t & 7)] = f2bf(pw0[o * 128 + t] * inv0);
        wfF1[((t >> 3) * 256 + o) * 8 + (t & 7)] = f2bf(pw1[o * 128 + t] * inv1);
    }
    wfF2[((t >> 3) * 256 + o) * 8 + (t & 7)] = f2bf(w2[o * 256 + t] * inv2);
}

// ---------------- GEMM helpers (32-px B-tile) ----------------
__device__ __forceinline__ void loadA0(const unsigned short* __restrict__ W,
                                       int wave, int l15, int l4, bf16x8 a[2]) {
    const int row0 = wave * 32 + l15;
    a[0] = *(const bf16x8*)(W + (l4 * 256 + row0) * 8);
    a[1] = *(const bf16x8*)(W + (l4 * 256 + row0 + 16) * 8);
}

// B-tile: [32 px][256 K] bf16, px-major 512 B/px, 16-B col c stored at c ^ ((px&15)<<4).
template<int NK>
__device__ __forceinline__ void gemm_expert(const char* lds, const unsigned short* __restrict__ W,
                                            int qb, int wave, int l15, int l4,
                                            const int* pxv, const int* swv,
                                            const bf16x8 aPre[2], f32x4 acc[2][2]) {
    const int row0 = wave * 32 + l15;
    bf16x8 aC[2], bC[2];
    aC[0] = aPre[0]; aC[1] = aPre[1];
#pragma unroll
    for (int tp = 0; tp < 2; ++tp)
        bC[tp] = *(const bf16x8*)(lds + pxv[tp] * 512 + ((qb + l4 * 16) ^ swv[tp]));

#pragma unroll
    for (int kk = 0; kk < NK; ++kk) {
        bf16x8 aN[2], bN[2];
        if (kk + 1 < NK) {
#pragma unroll
            for (int ot = 0; ot < 2; ++ot)
                aN[ot] = *(const bf16x8*)(W + (((kk + 1) * 4 + l4) * 256 + row0 + ot * 16) * 8);
#pragma unroll
            for (int tp = 0; tp < 2; ++tp)
                bN[tp] = *(const bf16x8*)(lds + pxv[tp] * 512 + ((qb + (kk + 1) * 64 + l4 * 16) ^ swv[tp]));
        }
#pragma unroll
        for (int ot = 0; ot < 2; ++ot)
#pragma unroll
            for (int tp = 0; tp < 2; ++tp)
                acc[ot][tp] = __builtin_amdgcn_mfma_f32_16x16x32_bf16(aC[ot], bC[tp], acc[ot][tp], 0, 0, 0);
        if (kk + 1 < NK) {
#pragma unroll
            for (int ot = 0; ot < 2; ++ot) aC[ot] = aN[ot];
#pragma unroll
            for (int tp = 0; tp < 2; ++tp) bC[tp] = bN[tp];
        }
    }
}

__device__ __forceinline__ void epilogue(const f32x4 acc[2][2], float ce, const float* __restrict__ bp,
                                         int wave, int l4, f32x4 res[2][2]) {
#pragma unroll
    for (int ot = 0; ot < 2; ++ot)
#pragma unroll
        for (int j = 0; j < 4; ++j) {
            const int o = wave * 32 + ot * 16 + l4 * 4 + j;
            const float bet = bp[o];
#pragma unroll
            for (int tp = 0; tp < 2; ++tp) {
                float v = acc[ot][tp][j] + bet;
                float sig = __builtin_amdgcn_rcpf(1.f + __expf(-v));
                res[ot][tp][j] += ce * (v * sig);
            }
        }
}

// ---------------- main fused kernel: 1 WG per (b,h,whalf), 8 waves ----------
// Block output: 256 outch x 32 px. LDS: [0,16K) dw B-tile; [16K,32K) raw B-tile;
// transpose epilogue reuses [0,36K).
__global__ __launch_bounds__(512, 4)
void fused_kernel(const float* __restrict__ x,
                  const float* __restrict__ wts, const int* __restrict__ idx,
                  const float* __restrict__ dw0, const float* __restrict__ dw1,
                  const unsigned short* __restrict__ wfF0,
                  const unsigned short* __restrict__ wfF1,
                  const unsigned short* __restrict__ wfF2,
                  const float* __restrict__ beta,
                  float* __restrict__ out) {
    __shared__ __align__(16) char lds[36864];

    const int tid  = threadIdx.x;
    const int wave = tid >> 6;
    const int lane = tid & 63;

    // XCD-aware swizzle on 4096 blocks (bijective): same XCD gets consecutive (b,h,whalf)
    const int bid = blockIdx.x;
    const int nb  = ((bid & 7) << 9) | (bid >> 3);
    const int whalf = nb & 1;
    const int h     = (nb >> 1) & 63;
    const int b     = nb >> 7;
    const int wlo   = whalf * 32;

    float c0 = 0.f, c1 = 0.f, c2 = 0.f;
#pragma unroll
    for (int t = 0; t < 2; ++t) {
        int e = idx[b * 2 + t];
        float w = wts[b * 2 + t];
        if (e == 0) c0 += w;
        else if (e == 1) c1 += w;
        else if (e == 2) c2 += w;
    }
    const bool do0 = (c0 != 0.f), do1 = (c1 != 0.f), do2 = (c2 != 0.f);

    const long rowBase = (long)b * 1048576L;

    const int g   = lane >> 3;                       // px-group 0..7 (4 px each)
    const int kq  = lane & 7;                        // channel slot 0..7
    const int px0 = g * 4;
    const int l15 = lane & 15;
    const int l4  = lane >> 4;
    const float* xr = x + rowBase + h * 64;
    const bool hm = (h > 0), hp = (h < 63);
    const bool wl_ok = (whalf == 1);                 // left neighbor col wlo-1 exists
    const bool wr_ok = (whalf == 0);                 // right neighbor col wlo+32 exists

    f32x4 res[2][2];
#pragma unroll
    for (int ot = 0; ot < 2; ++ot)
#pragma unroll
        for (int tp = 0; tp < 2; ++tp)
            res[ot][tp] = (f32x4){0.f, 0.f, 0.f, 0.f};

    int pxv[2], swv[2];
#pragma unroll
    for (int tp = 0; tp < 2; ++tp) {
        pxv[tp] = tp * 16 + l15;
        swv[tp] = (pxv[tp] & 15) << 4;
    }

    const bool dwact = (wave < 4) ? do0 : do1;
    const bool stg = dwact || do2;
    const float4 z4 = make_float4(0.f, 0.f, 0.f, 0.f);

    // ============ staging: one burst of 12 float4 + edge scalars, then compute ============
    float4 mR[2][2], cR[2][2], pR[2][2];
    float lx[2][2][3], rx[2][2][3];
    if (stg) {
#pragma unroll
        for (int pp = 0; pp < 2; ++pp) {
#pragma unroll
            for (int q = 0; q < 2; ++q) {
                const int k = wave * 32 + pp * 16 + kq * 2 + q;
                const float* base = xr + (long)k * 4096 + wlo + px0;
                cR[pp][q] = *(const float4*)base;
                if (dwact) {
                    mR[pp][q] = hm ? *(const float4*)(base - 64) : z4;
                    pR[pp][q] = hp ? *(const float4*)(base + 64) : z4;
                    // edge scalars (predicated; only g==0 / g==7 lanes use them)
                    lx[pp][q][0] = (g == 0 && wl_ok && hm) ? xr[(long)k * 4096 - 64 + wlo - 1] : 0.f;
                    lx[pp][q][1] = (g == 0 && wl_ok)       ? xr[(long)k * 4096 + wlo - 1]       : 0.f;
                    lx[pp][q][2] = (g == 0 && wl_ok && hp) ? xr[(long)k * 4096 + 64 + wlo - 1]  : 0.f;
                    rx[pp][q][0] = (g == 7 && wr_ok && hm) ? xr[(long)k * 4096 - 64 + wlo + 32] : 0.f;
                    rx[pp][q][1] = (g == 7 && wr_ok)       ? xr[(long)k * 4096 + wlo + 32]      : 0.f;
                    rx[pp][q][2] = (g == 7 && wr_ok && hp) ? xr[(long)k * 4096 + 64 + wlo + 32] : 0.f;
                }
            }
        }
#pragma unroll
        for (int pp = 0; pp < 2; ++pp) {
            const int kA = wave * 32 + pp * 16 + kq * 2;     // even channel
            float y[2][4];
            if (dwact) {
#pragma unroll
                for (int q = 0; q < 2; ++q) {
                    const int k = kA + q;
                    const float* dwp = (k < 128) ? (dw0 + k * 9) : (dw1 + (k - 128) * 9);
                    float4 m = mR[pp][q], c = cR[pp][q], p = pR[pp][q];
                    float lm = __shfl_up(m.w, 8), lc = __shfl_up(c.w, 8), lp = __shfl_up(p.w, 8);
                    float Rm = __shfl_down(m.x, 8), Rc = __shfl_down(c.x, 8), Rp = __shfl_down(p.x, 8);
                    if (g == 0) { lm = lx[pp][q][0]; lc = lx[pp][q][1]; lp = lx[pp][q][2]; }
                    if (g == 7) { Rm = rx[pp][q][0]; Rc = rx[pp][q][1]; Rp = rx[pp][q][2]; }
                    const float w0 = dwp[0], w1 = dwp[1], w2 = dwp[2];
                    const float w3 = dwp[3], w4 = dwp[4], w5 = dwp[5];
                    const float w6 = dwp[6], w7 = dwp[7], w8 = dwp[8];
                    y[q][0] = w0*lm  + w1*m.x + w2*m.y + w3*lc  + w4*c.x + w5*c.y + w6*lp  + w7*p.x + w8*p.y;
                    y[q][1] = w0*m.x + w1*m.y + w2*m.z + w3*c.x + w4*c.y + w5*c.z + w6*p.x + w7*p.y + w8*p.z;
                    y[q][2] = w0*m.y + w1*m.z + w2*m.w + w3*c.y + w4*c.z + w5*c.w + w6*p.y + w7*p.z + w8*p.w;
                    y[q][3] = w0*m.z + w1*m.w + w2*Rm  + w3*c.z + w4*c.w + w5*Rc  + w6*p.z + w7*p.w + w8*Rp;
                }
            }
            const int colb = (kA >> 3) * 16;
            const int sub  = (kA & 7) * 2;           // kA even -> 4B aligned
#pragma unroll
            for (int j = 0; j < 4; ++j) {
                const int px  = px0 + j;
                const int off = px * 512 + ((colb ^ ((px & 15) << 4))) + sub;
                if (dwact)
                    *(unsigned*)(lds + off) = pk_bf16(y[0][j], y[1][j]);
                if (do2)
                    *(unsigned*)(lds + 16384 + off) = pk_bf16(fcomp(cR[pp][0], j), fcomp(cR[pp][1], j));
            }
        }
    }

    // first A-frags for e0 hide under the barrier drain
    bf16x8 a0[2];
    loadA0(wfF0, wave, l15, l4, a0);

    __syncthreads();

    // ============ GEMM phases with next-expert A prefetch under epilogue ============
    f32x4 acc[2][2];
    if (do0) {
#pragma unroll
        for (int ot = 0; ot < 2; ++ot)
#pragma unroll
            for (int tp = 0; tp < 2; ++tp) acc[ot][tp] = (f32x4){0.f, 0.f, 0.f, 0.f};
        gemm_expert<4>(lds, wfF0, 0, wave, l15, l4, pxv, swv, a0, acc);
    }
    bf16x8 a1[2];
    loadA0(wfF1, wave, l15, l4, a1);
    if (do0) epilogue(acc, c0, beta, wave, l4, res);

    if (do1) {
#pragma unroll
        for (int ot = 0; ot < 2; ++ot)
#pragma unroll
            for (int tp = 0; tp < 2; ++tp) acc[ot][tp] = (f32x4){0.f, 0.f, 0.f, 0.f};
        gemm_expert<4>(lds, wfF1, 256, wave, l15, l4, pxv, swv, a1, acc);
    }
    bf16x8 a2[2];
    loadA0(wfF2, wave, l15, l4, a2);
    if (do1) epilogue(acc, c1, beta + 256, wave, l4, res);

    if (do2) {
#pragma unroll
        for (int ot = 0; ot < 2; ++ot)
#pragma unroll
            for (int tp = 0; tp < 2; ++tp) acc[ot][tp] = (f32x4){0.f, 0.f, 0.f, 0.f};
        gemm_expert<8>(lds + 16384, wfF2, 0, wave, l15, l4, pxv, swv, a2, acc);
        epilogue(acc, c2, beta + 512, wave, l4, res);
    }

    // ============ store: transpose through LDS ([256 outch][36] floats) ============
    float* lf = (float*)lds;
    const long outB = rowBase + h * 64 + wlo;
    __syncthreads();                                 // all waves done reading B-tiles
#pragma unroll
    for (int ot = 0; ot < 2; ++ot)
#pragma unroll
        for (int j = 0; j < 4; ++j) {
            const int o = wave * 32 + ot * 16 + l4 * 4 + j;   // 0..255
#pragma unroll
            for (int tp = 0; tp < 2; ++tp)
                lf[o * 36 + tp * 16 + l15] = res[ot][tp][j];
        }
    __syncthreads();
    {
        const int row = tid >> 1;                    // 0..255 outch
        const int col = (tid & 1) * 16;              // float index
        float* op = out + outB + (long)row * 4096 + col;
#pragma unroll
        for (int cc = 0; cc < 4; ++cc) {
            float4 v = *(float4*)&lf[row * 36 + col + cc * 4];
            *(float4*)(op + cc * 4) = v;
        }
    }
}

extern "C" void kernel_launch(void* const* d_in, const int* in_sizes, int n_in,
                              void* d_out, int out_size, void* d_ws, size_t ws_size,
                              hipStream_t stream) {
    const float* x    = (const float*)d_in[0];
    const float* wts  = (const float*)d_in[1];
    const int*   idx  = (const int*)d_in[2];
    const float* dw0  = (const float*)d_in[3];
    const float* pw0  = (const float*)d_in[4];
    const float* s0   = (const float*)d_in[5];
    const float* b0   = (const float*)d_in[6];
    const float* m0   = (const float*)d_in[7];
    const float* v0   = (const float*)d_in[8];
    const float* dw1  = (const float*)d_in[9];
    const float* pw1  = (const float*)d_in[10];
    const float* s1   = (const float*)d_in[11];
    const float* b1   = (const float*)d_in[12];
    const float* m1   = (const float*)d_in[13];
    const float* v1   = (const float*)d_in[14];
    const float* w2   = (const float*)d_in[15];
    const float* s2   = (const float*)d_in[16];
    const float* b2   = (const float*)d_in[17];
    const float* m2   = (const float*)d_in[18];
    const float* v2   = (const float*)d_in[19];

    char* ws = (char*)d_ws;
    unsigned short* wfF0 = (unsigned short*)ws;                 // 64 KB
    unsigned short* wfF1 = (unsigned short*)(ws + 65536);       // 64 KB
    unsigned short* wfF2 = (unsigned short*)(ws + 131072);      // 128 KB
    float*          beta = (float*)(ws + 262144);               // 3 KB

    prep_kernel<<<256, 256, 0, stream>>>(pw0, pw1, w2,
                                         s0, b0, m0, v0,
                                         s1, b1, m1, v1,
                                         s2, b2, m2, v2,
                                         wfF0, wfF1, wfF2, beta);

    fused_kernel<<<4096, 512, 0, stream>>>(x, wts, idx, dw0, dw1,
                                           wfF0, wfF1, wfF2, beta, (float*)d_out);
}

// Round 12
// 97.000 us; speedup vs baseline: 1.3193x; 1.3193x over previous
//
#include <hip/hip_runtime.h>

typedef __bf16 bf16x8 __attribute__((ext_vector_type(8)));
typedef float f32x4 __attribute__((ext_vector_type(4)));

#define BN_EPS 1e-5f

__device__ __forceinline__ unsigned short f2bf(float f) {
    union { float f; unsigned u; } x; x.f = f;
    unsigned r = x.u + 0x7fffu + ((x.u >> 16) & 1u);
    return (unsigned short)(r >> 16);
}

__device__ __forceinline__ unsigned pk_bf16(float lo, float hi) {
    unsigned r;
    asm("v_cvt_pk_bf16_f32 %0, %1, %2" : "=v"(r) : "v"(lo), "v"(hi));
    return r;
}

__device__ __forceinline__ float fcomp(float4 v, int j) {
    return (j == 0) ? v.x : (j == 1) ? v.y : (j == 2) ? v.z : v.w;
}

// ---------------- prepass: fold BN scale into weights (frag-contiguous) + padded dw ----
__global__ void prep_kernel(const float* __restrict__ pw0, const float* __restrict__ pw1,
                            const float* __restrict__ w2,
                            const float* __restrict__ dw0, const float* __restrict__ dw1,
                            const float* __restrict__ s0, const float* __restrict__ b0,
                            const float* __restrict__ m0, const float* __restrict__ v0,
                            const float* __restrict__ s1, const float* __restrict__ b1,
                            const float* __restrict__ m1, const float* __restrict__ v1,
                            const float* __restrict__ s2, const float* __restrict__ b2,
                            const float* __restrict__ m2, const float* __restrict__ v2,
                            unsigned short* __restrict__ wfF0, unsigned short* __restrict__ wfF1,
                            unsigned short* __restrict__ wfF2, float* __restrict__ beta,
                            float* __restrict__ wpad) {
    int o = blockIdx.x;     // 0..255 (outch, and channel for wpad)
    int t = threadIdx.x;    // 0..255
    float inv0 = s0[o] * rsqrtf(v0[o] + BN_EPS);
    float inv1 = s1[o] * rsqrtf(v1[o] + BN_EPS);
    float inv2 = s2[o] * rsqrtf(v2[o] + BN_EPS);
    if (t == 0) {
        beta[0 * 256 + o] = b0[o] - m0[o] * inv0;
        beta[1 * 256 + o] = b1[o] - m1[o] * inv1;
        beta[2 * 256 + o] = b2[o] - m2[o] * inv2;
    }
    if (t < 12) {
        float v = 0.f;
        if (t < 9) v = (o < 128) ? dw0[o * 9 + t] : dw1[(o - 128) * 9 + t];
        wpad[o * 12 + t] = v;
    }
    if (t < 128) {
        wfF0[((t >> 3) * 256 + o) * 8 + (t & 7)] = f2bf(pw0[o * 128 + t] * inv0);
        wfF1[((t >> 3) * 256 + o) * 8 + (t & 7)] = f2bf(pw1[o * 128 + t] * inv1);
    }
    wfF2[((t >> 3) * 256 + o) * 8 + (t & 7)] = f2bf(w2[o * 256 + t] * inv2);
}

// ---------------- GEMM helper: r7 structure (kk-outer, depth-1 prefetch) --------------
// B-tile: [64 px][256 K] bf16, px-major 512 B/px, 16-B col c stored at c ^ ((px&15)<<4).
template<int NK>
__device__ __forceinline__ void gemm_expert(const char* lds, const unsigned short* __restrict__ W,
                                            int qb, int wave, int l15, int l4,
                                            const int* pxv, const int* swv, f32x4 acc[2][4]) {
    const int row0 = wave * 32 + l15;
    bf16x8 aC[2], bC[4];
#pragma unroll
    for (int ot = 0; ot < 2; ++ot)
        aC[ot] = *(const bf16x8*)(W + (l4 * 256 + row0 + ot * 16) * 8);
#pragma unroll
    for (int tp = 0; tp < 4; ++tp)
        bC[tp] = *(const bf16x8*)(lds + pxv[tp] * 512 + ((qb + l4 * 16) ^ swv[tp]));

#pragma unroll
    for (int kk = 0; kk < NK; ++kk) {
        bf16x8 aN[2], bN[4];
        if (kk + 1 < NK) {
#pragma unroll
            for (int ot = 0; ot < 2; ++ot)
                aN[ot] = *(const bf16x8*)(W + (((kk + 1) * 4 + l4) * 256 + row0 + ot * 16) * 8);
#pragma unroll
            for (int tp = 0; tp < 4; ++tp)
                bN[tp] = *(const bf16x8*)(lds + pxv[tp] * 512 + ((qb + (kk + 1) * 64 + l4 * 16) ^ swv[tp]));
        }
#pragma unroll
        for (int ot = 0; ot < 2; ++ot)
#pragma unroll
            for (int tp = 0; tp < 4; ++tp)
                acc[ot][tp] = __builtin_amdgcn_mfma_f32_16x16x32_bf16(aC[ot], bC[tp], acc[ot][tp], 0, 0, 0);
        if (kk + 1 < NK) {
#pragma unroll
            for (int ot = 0; ot < 2; ++ot) aC[ot] = aN[ot];
#pragma unroll
            for (int tp = 0; tp < 4; ++tp) bC[tp] = bN[tp];
        }
    }
}

__device__ __forceinline__ void epilogue(const f32x4 acc[2][4], float ce, const float* __restrict__ bp,
                                         int wave, int l4, f32x4 res[2][4]) {
#pragma unroll
    for (int ot = 0; ot < 2; ++ot)
#pragma unroll
        for (int j = 0; j < 4; ++j) {
            const int o = wave * 32 + ot * 16 + l4 * 4 + j;
            const float bet = bp[o];
#pragma unroll
            for (int tp = 0; tp < 4; ++tp) {
                float v = acc[ot][tp][j] + bet;
                float sig = __builtin_amdgcn_rcpf(1.f + __expf(-v));
                res[ot][tp][j] += ce * (v * sig);
            }
        }
}

// ---------------- main fused kernel: 1 WG per (b,h) row, 8 waves, 2 K-passes ----------
__global__ __launch_bounds__(512, 4)
void fused_kernel(const float* __restrict__ x,
                  const float* __restrict__ wts, const int* __restrict__ idx,
                  const float* __restrict__ wpad,
                  const unsigned short* __restrict__ wfF0,
                  const unsigned short* __restrict__ wfF1,
                  const unsigned short* __restrict__ wfF2,
                  const float* __restrict__ beta,
                  float* __restrict__ out) {
    __shared__ __align__(16) char lds[34816];        // B-tile 32 KB; transpose 34.8 KB

    const int tid  = threadIdx.x;
    const int wave = tid >> 6;
    const int lane = tid & 63;

    const int bid = blockIdx.x;
    const int nb  = ((bid & 7) << 8) | (bid >> 3);   // XCD swizzle, bijective on 2048
    const int b   = nb >> 6;
    const int h   = nb & 63;

    float c0 = 0.f, c1 = 0.f, c2 = 0.f;
#pragma unroll
    for (int t = 0; t < 2; ++t) {
        int e = idx[b * 2 + t];
        float w = wts[b * 2 + t];
        if (e == 0) c0 += w;
        else if (e == 1) c1 += w;
        else if (e == 2) c2 += w;
    }
    const bool do0 = (c0 != 0.f), do1 = (c1 != 0.f), do2 = (c2 != 0.f);

    const long rowBase = (long)b * 1048576L;

    const int g   = lane >> 2;                       // pass-2 mapping: px-group 0..15
    const int kq  = lane & 3;
    const int px0 = g * 4;
    const int l15 = lane & 15;
    const int l4  = lane >> 4;
    const float* xb = x + rowBase + h * 64 + px0;
    const bool hm = (h > 0), hp = (h < 63);
    const float4 z4 = make_float4(0.f, 0.f, 0.f, 0.f);

    f32x4 res[2][4];
#pragma unroll
    for (int ot = 0; ot < 2; ++ot)
#pragma unroll
        for (int tp = 0; tp < 4; ++tp)
            res[ot][tp] = (f32x4){0.f, 0.f, 0.f, 0.f};

    int pxv[4], swv[4];
#pragma unroll
    for (int tp = 0; tp < 4; ++tp) {
        pxv[tp] = tp * 16 + l15;
        swv[tp] = (pxv[tp] & 15) << 4;
    }

    // ================= pass 1: depthwise experts (K 0..255 = dw0 | dw1) ==============
    // NEW mapping: each thread = 4 channels x 8 px. 36 VMEM/thread (was 96).
    if (do0 || do1) {
        const bool dwact = (wave < 4) ? do0 : do1;
        if (dwact) {
            const int g2  = lane >> 3;               // px octet 0..7
            const int kq2 = lane & 7;                // ch quad slot
            const int px8 = g2 * 8;
            const int k0  = wave * 32 + kq2 * 4;     // 4 channels k0..k0+3
            const float* xw = x + rowBase + h * 64 + px8;
            const bool glz = (g2 == 0), grz = (g2 == 7);
#pragma unroll
            for (int pr = 0; pr < 2; ++pr) {         // channel pair
                float y[2][8];
#pragma unroll
                for (int c = 0; c < 2; ++c) {
                    const int k = k0 + pr * 2 + c;
                    const float* xc = xw + (long)k * 4096;
                    float4 m0 = hm ? *(const float4*)(xc - 64) : z4;
                    float4 m1 = hm ? *(const float4*)(xc - 60) : z4;
                    float4 cv0 = *(const float4*)(xc);
                    float4 cv1 = *(const float4*)(xc + 4);
                    float4 p0 = hp ? *(const float4*)(xc + 64) : z4;
                    float4 p1 = hp ? *(const float4*)(xc + 68) : z4;
                    const float4 wA = *(const float4*)(wpad + k * 12);
                    const float4 wB = *(const float4*)(wpad + k * 12 + 4);
                    const float  w8v = wpad[k * 12 + 8];
                    float lm = __shfl_up(m1.w, 8), lc = __shfl_up(cv1.w, 8), lp = __shfl_up(p1.w, 8);
                    float Rm = __shfl_down(m0.x, 8), Rc = __shfl_down(cv0.x, 8), Rp = __shfl_down(p0.x, 8);
                    if (glz) { lm = 0.f; lc = 0.f; lp = 0.f; }
                    if (grz) { Rm = 0.f; Rc = 0.f; Rp = 0.f; }
                    const float mr[10] = {lm, m0.x, m0.y, m0.z, m0.w, m1.x, m1.y, m1.z, m1.w, Rm};
                    const float cr[10] = {lc, cv0.x, cv0.y, cv0.z, cv0.w, cv1.x, cv1.y, cv1.z, cv1.w, Rc};
                    const float pq[10] = {lp, p0.x, p0.y, p0.z, p0.w, p1.x, p1.y, p1.z, p1.w, Rp};
#pragma unroll
                    for (int j = 0; j < 8; ++j)
                        y[c][j] = wA.x * mr[j] + wA.y * mr[j + 1] + wA.z * mr[j + 2]
                                + wA.w * cr[j] + wB.x * cr[j + 1] + wB.y * cr[j + 2]
                                + wB.z * pq[j] + wB.w * pq[j + 1] + w8v * pq[j + 2];
                }
                const int colb = (k0 >> 3) * 16;
                const int sub  = ((k0 & 4) << 1) + pr * 4;
#pragma unroll
                for (int j = 0; j < 8; ++j) {
                    const int px = px8 + j;
                    *(unsigned*)(lds + px * 512 + ((colb ^ ((px & 15) << 4))) + sub) =
                        pk_bf16(y[0][j], y[1][j]);
                }
            }
        }
        __syncthreads();
        if (do0) {
            f32x4 acc[2][4];
#pragma unroll
            for (int ot = 0; ot < 2; ++ot)
#pragma unroll
                for (int tp = 0; tp < 4; ++tp) acc[ot][tp] = (f32x4){0.f, 0.f, 0.f, 0.f};
            gemm_expert<4>(lds, wfF0, 0, wave, l15, l4, pxv, swv, acc);
            epilogue(acc, c0, beta, wave, l4, res);
        }
        if (do1) {
            f32x4 acc[2][4];
#pragma unroll
            for (int ot = 0; ot < 2; ++ot)
#pragma unroll
                for (int tp = 0; tp < 4; ++tp) acc[ot][tp] = (f32x4){0.f, 0.f, 0.f, 0.f};
            gemm_expert<4>(lds, wfF1, 256, wave, l15, l4, pxv, swv, acc);
            epilogue(acc, c1, beta + 256, wave, l4, res);
        }
    }

    // ================= pass 2: raw expert (K 0..255 = x channels) ====================
    if (do2) {
        __syncthreads();                             // pass-1 readers done before overwrite
        {
            const int cb = wave * 32 + kq * 8;       // 8 channels
            float4 r[8];
#pragma unroll
            for (int c = 0; c < 8; ++c)
                r[c] = *(const float4*)(xb + (long)(cb + c) * 4096);
            const int colb = (cb >> 3) * 16;
#pragma unroll
            for (int j = 0; j < 4; ++j) {
                const int px = px0 + j;
                float v0 = fcomp(r[0], j), v1 = fcomp(r[1], j), v2 = fcomp(r[2], j), v3 = fcomp(r[3], j);
                float v4 = fcomp(r[4], j), v5 = fcomp(r[5], j), v6 = fcomp(r[6], j), v7 = fcomp(r[7], j);
                *(uint4*)(lds + px * 512 + ((colb ^ ((px & 15) << 4)))) =
                    make_uint4(pk_bf16(v0, v1), pk_bf16(v2, v3), pk_bf16(v4, v5), pk_bf16(v6, v7));
            }
        }
        __syncthreads();
        {
            f32x4 acc[2][4];
#pragma unroll
            for (int ot = 0; ot < 2; ++ot)
#pragma unroll
                for (int tp = 0; tp < 4; ++tp) acc[ot][tp] = (f32x4){0.f, 0.f, 0.f, 0.f};
            gemm_expert<8>(lds, wfF2, 0, wave, l15, l4, pxv, swv, acc);
            epilogue(acc, c2, beta + 512, wave, l4, res);
        }
    }

    // ================= store: transpose through LDS, full-line writes ================
    float* lf = (float*)lds;
    const long outB = rowBase + h * 64;
    __syncthreads();
#pragma unroll
    for (int r = 0; r < 2; ++r) {
        if ((wave >> 2) == r) {
#pragma unroll
            for (int ot = 0; ot < 2; ++ot)
#pragma unroll
                for (int j = 0; j < 4; ++j) {
                    const int o = wave * 32 + ot * 16 + l4 * 4 + j;
#pragma unroll
                    for (int tp = 0; tp < 4; ++tp)
                        lf[(o & 127) * 68 + tp * 16 + l15] = res[ot][tp][j];
                }
        }
        __syncthreads();
        {
            const int rowq = tid >> 3;               // 0..63
            const int col  = (tid & 7) * 8;          // float index
#pragma unroll
            for (int rr = 0; rr < 2; ++rr) {
                const int lr = rowq + rr * 64;       // 0..127
                float4 v0 = *(float4*)&lf[lr * 68 + col];
                float4 v1 = *(float4*)&lf[lr * 68 + col + 4];
                float* op = out + outB + (long)(r * 128 + lr) * 4096 + col;
                *(float4*)op = v0;
                *(float4*)(op + 4) = v1;
            }
        }
        __syncthreads();
    }
}

extern "C" void kernel_launch(void* const* d_in, const int* in_sizes, int n_in,
                              void* d_out, int out_size, void* d_ws, size_t ws_size,
                              hipStream_t stream) {
    const float* x    = (const float*)d_in[0];
    const float* wts  = (const float*)d_in[1];
    const int*   idx  = (const int*)d_in[2];
    const float* dw0  = (const float*)d_in[3];
    const float* pw0  = (const float*)d_in[4];
    const float* s0   = (const float*)d_in[5];
    const float* b0   = (const float*)d_in[6];
    const float* m0   = (const float*)d_in[7];
    const float* v0   = (const float*)d_in[8];
    const float* dw1  = (const float*)d_in[9];
    const float* pw1  = (const float*)d_in[10];
    const float* s1   = (const float*)d_in[11];
    const float* b1   = (const float*)d_in[12];
    const float* m1   = (const float*)d_in[13];
    const float* v1   = (const float*)d_in[14];
    const float* w2   = (const float*)d_in[15];
    const float* s2   = (const float*)d_in[16];
    const float* b2   = (const float*)d_in[17];
    const float* m2   = (const float*)d_in[18];
    const float* v2   = (const float*)d_in[19];

    char* ws = (char*)d_ws;
    unsigned short* wfF0 = (unsigned short*)ws;                 // 64 KB
    unsigned short* wfF1 = (unsigned short*)(ws + 65536);       // 64 KB
    unsigned short* wfF2 = (unsigned short*)(ws + 131072);      // 128 KB
    float*          beta = (float*)(ws + 262144);               // 3 KB
    float*          wpad = (float*)(ws + 265216);               // 12 KB padded dw weights

    prep_kernel<<<256, 256, 0, stream>>>(pw0, pw1, w2, dw0, dw1,
                                         s0, b0, m0, v0,
                                         s1, b1, m1, v1,
                                         s2, b2, m2, v2,
                                         wfF0, wfF1, wfF2, beta, wpad);

    fused_kernel<<<2048, 512, 0, stream>>>(x, wts, idx, wpad,
                                           wfF0, wfF1, wfF2, beta, (float*)d_out);
}